// Round 23
// baseline (63.998 us; speedup 1.0000x reference)
//
#include <hip/hip_runtime.h>

// Output layout (flat f32, reference return order):
//   out0 : (1024,50,3)  @ 0       (153600)
//   steps: (1024,3,49)  @ 153600  (150528)  all 0.01
//   eps  : (1024,3)     @ 304128  (3072)    analytic 0
//   var  : (1024,50,3)  @ 307200  (153600)
//   xi   : (1,10,3)     @ 460800  (30)
#define OUT0_OFF  0
#define STEPS_OFF 153600
#define EPS_OFF   304128
#define VAR_OFF   307200
#define XI_OFF    460800

typedef short bf16x8 __attribute__((ext_vector_type(8)));
typedef float f32x4  __attribute__((ext_vector_type(4)));
typedef unsigned short u16x8 __attribute__((ext_vector_type(8)));
typedef unsigned short u16x4 __attribute__((ext_vector_type(4)));

__device__ __forceinline__ unsigned short f2bf(float x) {   // RNE f32->bf16
    union { float f; unsigned u; } c; c.f = x;
    return (unsigned short)((c.u + 0x7FFFu + ((c.u >> 16) & 1u)) >> 16);
}
__device__ __forceinline__ float bf2f(unsigned short h) {
    union { float f; unsigned u; } c; c.u = ((unsigned)h) << 16;
    return c.f;
}

__device__ __forceinline__ void fma16v(const float4& av, const float4& bv,
                                       float acc[4][4]) {
    const float a_[4] = {av.x, av.y, av.z, av.w};
    const float b_[4] = {bv.x, bv.y, bv.z, bv.w};
    #pragma unroll
    for (int i = 0; i < 4; ++i)
        #pragma unroll
        for (int j = 0; j < 4; ++j)
            acc[i][j] = fmaf(a_[i], b_[j], acc[i][j]);
}

// ------- transpose+split (bx<16: nW2; 16<=bx<19: nW3) + mv1 (bx==19) ----------
__global__ __launch_bounds__(256)
void transp_both(const float* __restrict__ w2,
                 unsigned short* __restrict__ t2h, unsigned short* __restrict__ t2l,
                 const float* __restrict__ w3,
                 unsigned short* __restrict__ t3h, unsigned short* __restrict__ t3l,
                 const float* __restrict__ px, const float* __restrict__ pW1,
                 const float* __restrict__ pb1, float* __restrict__ h1p)
{
    __shared__ float Ts[64][65];
    const int t = threadIdx.x;

    if (blockIdx.x == 19) {                       // mv1: 16 blocks x 64 j
        float* red = &Ts[0][0];                   // [4][64]
        const int jl = t & 63, kg = t >> 6;       // 4 kgroups x 16 k
        const int j = blockIdx.y * 64 + jl;
        float acc = 0.f;
        for (int k = kg * 16; k < kg * 16 + 16; ++k)
            acc = fmaf(px[k], pW1[k * 1024 + j], acc);
        red[kg * 64 + jl] = acc;
        __syncthreads();
        if (kg == 0) {
            float s = red[jl] + red[64 + jl] + red[128 + jl] + red[192 + jl];
            h1p[j] = fmaxf(s + pb1[j], 0.f);
        }
        return;
    }

    const bool w3path = blockIdx.x >= 16;
    const int n0 = (w3path ? (blockIdx.x - 16) : blockIdx.x) * 64;
    const int k0 = blockIdx.y * 64;
    const int g = t >> 6;
    const int l = t & 63;
    #pragma unroll
    for (int i = 0; i < 16; ++i) {
        const int kl = g * 16 + i;
        if (w3path) {
            const int n = n0 + l;
            Ts[kl][l] = (n < 150) ? w3[(k0 + kl) * 150 + n] : 0.f;
        } else {
            Ts[kl][l] = w2[(k0 + kl) * 1024 + n0 + l];
        }
    }
    __syncthreads();
    unsigned short* th = w3path ? t3h : t2h;
    unsigned short* tl = w3path ? t3l : t2l;
    #pragma unroll
    for (int i = 0; i < 16; ++i) {
        const int nl = g * 16 + i;
        const float x = Ts[l][nl];
        const unsigned short h = f2bf(x);
        th[(long)(n0 + nl) * 1024 + k0 + l] = h;
        tl[(long)(n0 + nl) * 1024 + k0 + l] = f2bf(x - bf2f(h));
    }
}

// ---------------- GEMM1 (+ mv2_part piggyback on bx==16) ----------------------
// H1 = relu(net_iv @ nW1 + nb1) -> bf16 hi/lo. bx==16: 32 blocks compute the
// mv2 k-slice partials part[16][1024] (4 slices x 128 j per block, coalesced).
__global__ __launch_bounds__(128)
void gemm1_k150(const float* __restrict__ A, const float* __restrict__ B,
                const float* __restrict__ bias,
                unsigned short* __restrict__ H1h, unsigned short* __restrict__ H1l,
                const float* __restrict__ h1p, const float* __restrict__ pW2,
                float* __restrict__ part)
{
    __shared__ __align__(16) float As[150][36];   // transposed A, 21.6 KB
    __shared__ __align__(16) float Bs[150][64];   // 38.4 KB
    const int t = threadIdx.x;

    if (blockIdx.x == 16) {                       // mv2_part: 32 blocks
        const int y = blockIdx.y;                 // 0..31
        const int j = (y & 7) * 128 + t;
        const int sg = y >> 3;                    // slice group 0..3
        float acc[4] = {};
        #pragma unroll
        for (int s = 0; s < 4; ++s) {
            const int k0 = (sg * 4 + s) * 64;
            #pragma unroll 8
            for (int k = k0; k < k0 + 64; ++k)
                acc[s] = fmaf(h1p[k], pW2[k * 1024 + j], acc[s]);
        }
        #pragma unroll
        for (int s = 0; s < 4; ++s)
            part[(sg * 4 + s) * 1024 + j] = acc[s];
        return;
    }

    const int col0 = blockIdx.x * 64;
    const int row0 = blockIdx.y * 32;

    for (int i = t; i < 4800; i += 128) {
        const int r = i / 150;
        const int k = i - r * 150;
        As[k][r] = A[row0 * 150 + i];
    }
    {
        const int c4 = (t & 15) * 4;
        for (int k = t >> 4; k < 150; k += 8)
            *(float4*)&Bs[k][c4] = *(const float4*)(B + k * 1024 + col0 + c4);
    }
    __syncthreads();

    const int tx4 = (t & 15) * 4;
    const int ty4 = (t >> 4) * 4;
    float acc[4][4] = {};
    float4 aA = *(const float4*)&As[0][ty4], bA = *(const float4*)&Bs[0][tx4];
    float4 aB = *(const float4*)&As[1][ty4], bB = *(const float4*)&Bs[1][tx4];
    #pragma unroll 5
    for (int k = 0; k < 150; k += 2) {
        float4 aN0 = {}, bN0 = {}, aN1 = {}, bN1 = {};
        if (k + 2 < 150) {
            aN0 = *(const float4*)&As[k + 2][ty4];
            bN0 = *(const float4*)&Bs[k + 2][tx4];
        }
        if (k + 3 < 150) {
            aN1 = *(const float4*)&As[k + 3][ty4];
            bN1 = *(const float4*)&Bs[k + 3][tx4];
        }
        fma16v(aA, bA, acc);
        fma16v(aB, bB, acc);
        aA = aN0; bA = bN0; aB = aN1; bB = bN1;
    }
    #pragma unroll
    for (int i = 0; i < 4; ++i) {
        const int r = row0 + ty4 + i;
        #pragma unroll
        for (int j = 0; j < 4; ++j) {
            const int c = col0 + tx4 + j;
            const float v = fmaxf(acc[i][j] + bias[c], 0.f);
            const unsigned short h = f2bf(v);
            H1h[r * 1024 + c] = h;
            H1l[r * 1024 + c] = f2bf(v - bf2f(h));
        }
    }
}

// ---------------- gemm2_mfma: 64x64 tile, split-K=2, K-step 64 ----------------
// Full-cache-line staging (8 lanes x 16 B = 128 B rows), nk=8, XCD-tile
// swizzle. z==2 layer: 4 blocks reduce mv2 partials -> hvec.
__global__ __launch_bounds__(256, 1)
void gemm2_mfma(const unsigned short* __restrict__ Ah, const unsigned short* __restrict__ Al,
                const unsigned short* __restrict__ Bh, const unsigned short* __restrict__ Bl,
                float* __restrict__ P2,
                const float* __restrict__ part, const float* __restrict__ pb2,
                float* __restrict__ hvec)
{
    // [buf][mat 4][kg8 * 528 + row * 8] shorts = 67.6 KB -> 2 blocks/CU
    __shared__ __align__(16) unsigned short L[2][4][4224];
    const int t = threadIdx.x;

    if (blockIdx.z == 2) {                         // mv2 reduce: 4 blocks
        const int idx = blockIdx.y * 16 + blockIdx.x;
        if (idx >= 4) return;
        const int j = idx * 256 + t;
        float s = 0.f;
        #pragma unroll
        for (int sl2 = 0; sl2 < 16; ++sl2) s += part[sl2 * 1024 + j];
        hvec[j] = fmaxf(s + pb2[j], 0.f);
        return;
    }

    // XCD-tile swizzle: xcd = x%8; per-XCD working set 3 MB <= 4 MB L2.
    const int x = blockIdx.x, y = blockIdx.y;
    const int xcd = x & 7;
    const int v   = ((x >> 3) << 4) + y;           // 0..31
    const int by  = (xcd >> 1) * 4 + (v & 3);      // 0..15
    const int bx  = (xcd & 1) * 8 + (v >> 2);      // 0..15
    const int m0 = by * 64;
    const int n0 = bx * 64;
    const int K = 1024, nk = 8;                    // kchunk 512, K-step 64
    const long kbase = (long)blockIdx.z * 512;

    const int sm = t >> 6;                         // wave stages one matrix
    const int sl = t & 63;
    const unsigned short* src = (sm == 0) ? Ah : (sm == 1) ? Al
                              : (sm == 2) ? Bh : Bl;
    const int srow0 = (sm < 2) ? m0 : n0;

    u16x8 gv[8];
    auto stage_load = [&](int kt) {                // T14: issue early
        const long kb = kbase + (long)kt * 64;
        #pragma unroll
        for (int c2 = 0; c2 < 8; ++c2) {
            const int flat = c2 * 64 + sl;
            const int row = flat >> 3, kg = flat & 7;   // 8 lanes/row = 128 B
            gv[c2] = *(const u16x8*)(src + (long)(srow0 + row) * K + kb + kg * 8);
        }
    };
    auto stage_write = [&](int buf) {              // T14: write late
        #pragma unroll
        for (int c2 = 0; c2 < 8; ++c2) {
            const int flat = c2 * 64 + sl;
            const int row = flat >> 3, kg = flat & 7;
            *(u16x8*)&L[buf][sm][kg * 528 + row * 8] = gv[c2];
        }
    };

    const int wv = t >> 6;
    const int r0 = (wv >> 1) * 32, c0 = (wv & 1) * 32;
    const int lane = t & 63, lr = lane & 15, kq = lane >> 4;

    f32x4 accH[2][2] = {};
    f32x4 accL[2][2] = {};
    stage_load(0);
    stage_write(0);
    __syncthreads();
    for (int kt = 0; kt < nk; ++kt) {
        const int buf = kt & 1;
        if (kt + 1 < nk) stage_load(kt + 1);
        const short* lb = (const short*)&L[buf][0][0];
        #pragma unroll
        for (int h = 0; h < 2; ++h) {              // two 32-k halves, old order
            const int kgf = kq + h * 4;
            bf16x8 fah[2], fal[2], fbh[2], fbl[2];
            #pragma unroll
            for (int rt = 0; rt < 2; ++rt) {
                const int o = kgf * 528 + (r0 + rt * 16 + lr) * 8;
                fah[rt] = *(const bf16x8*)(lb + o);
                fal[rt] = *(const bf16x8*)(lb + 4224 + o);
            }
            #pragma unroll
            for (int ct = 0; ct < 2; ++ct) {
                const int o = kgf * 528 + (c0 + ct * 16 + lr) * 8;
                fbh[ct] = *(const bf16x8*)(lb + 8448 + o);
                fbl[ct] = *(const bf16x8*)(lb + 12672 + o);
            }
            #pragma unroll
            for (int rt = 0; rt < 2; ++rt)
                #pragma unroll
                for (int ct = 0; ct < 2; ++ct) {
                    accH[rt][ct] = __builtin_amdgcn_mfma_f32_16x16x32_bf16(
                                       fah[rt], fbh[ct], accH[rt][ct], 0, 0, 0);
                    accL[rt][ct] = __builtin_amdgcn_mfma_f32_16x16x32_bf16(
                                       fah[rt], fbl[ct], accL[rt][ct], 0, 0, 0);
                    accL[rt][ct] = __builtin_amdgcn_mfma_f32_16x16x32_bf16(
                                       fal[rt], fbh[ct], accL[rt][ct], 0, 0, 0);
                }
        }
        if (kt + 1 < nk) stage_write(buf ^ 1);
        __syncthreads();
    }

    // C/D layout: row = (lane>>4)*4 + j, col = lane&15  [m89-verified]
    float* Cb = P2 + (long)blockIdx.z * 1048576;
    #pragma unroll
    for (int rt = 0; rt < 2; ++rt)
        #pragma unroll
        for (int ct = 0; ct < 2; ++ct)
            #pragma unroll
            for (int j = 0; j < 4; ++j)
                Cb[(long)(m0 + r0 + rt * 16 + kq * 4 + j) * 1024 +
                   (n0 + c0 + ct * 16 + lr)] = accH[rt][ct][j] + accL[rt][ct][j];
}

// ---------------- gemm3_mfma: A-stage fuses P2-reduce+bias+relu+split ---------
// Grid (64,8), XCD co-located A-panels; bxi==3 -> mv3 (reads hvec).
__global__ __launch_bounds__(256, 1)
void gemm3_mfma(const float* __restrict__ P2, const float* __restrict__ nb2,
                const unsigned short* __restrict__ Bh, const unsigned short* __restrict__ Bl,
                float* __restrict__ P3,
                const float* __restrict__ hvec,
                const float* __restrict__ pW3, const float* __restrict__ pb3,
                const float* __restrict__ mask, float* __restrict__ xi)
{
    __shared__ __align__(16) unsigned short L[2][4][2112];
    const int t = threadIdx.x;

    const int g   = blockIdx.x;                    // 0..63
    const int sk  = blockIdx.y;                    // 0..7
    const int bxi = (g >> 3) & 3;                  // 0..3
    const int by  = (g & 7) + ((g >> 5) << 3);     // 0..15

    if (bxi == 3) {                                // mv3: 15 blocks x 2 j
        const int idx = by * 8 + sk;
        if (idx >= 15) return;
        const int j = idx * 2 + (t >> 7);
        const int lane = t & 127;
        float acc = 0.f;
        for (int k = lane; k < 1024; k += 128)
            acc = fmaf(hvec[k], pW3[k * 30 + j], acc);
        #pragma unroll
        for (int off = 32; off > 0; off >>= 1) acc += __shfl_down(acc, off, 64);
        float* red = (float*)&L[0][0][0];
        if ((t & 63) == 0) red[t >> 6] = acc;
        __syncthreads();
        if ((t & 127) == 0)
            xi[j] = (red[t >> 6] + red[(t >> 6) + 1] + pb3[j]) * mask[j];
        return;
    }

    const int m0 = by * 64;
    const int n0 = bxi * 64;
    const int nk = 4;                              // kchunk 128
    const long kbase = (long)sk * 128;

    float4 ga[2][2];                               // [c][partial-sum parts]
    u16x8 gb[2];
    auto stage_load = [&](int kt) {
        const long kb = kbase + (long)kt * 32;
        #pragma unroll
        for (int c = 0; c < 2; ++c) {
            const int idx = c * 256 + t;           // 0..511
            const int row = idx >> 3, q = idx & 7; // 64 rows x 8 f32-quads
            const long o = (long)(m0 + row) * 1024 + kb + q * 4;
            float4 p = *(const float4*)(P2 + o);
            float4 s = *(const float4*)(P2 + 1048576 + o);
            float4 bv = *(const float4*)(nb2 + kb + q * 4);
            ga[c][0].x = p.x + s.x + bv.x; ga[c][0].y = p.y + s.y + bv.y;
            ga[c][0].z = p.z + s.z + bv.z; ga[c][0].w = p.w + s.w + bv.w;
            ga[c][1] = ga[c][0];                   // placeholder (unused slot)
        }
        {
            const int row = t >> 2, kg = t & 3;    // 64 rows x 4 kgroups
            const long o = (long)(n0 + row) * 1024 + kb + kg * 8;
            gb[0] = *(const u16x8*)(Bh + o);
            gb[1] = *(const u16x8*)(Bl + o);
        }
    };
    auto stage_write = [&](int buf) {
        #pragma unroll
        for (int c = 0; c < 2; ++c) {
            const int idx = c * 256 + t;
            const int row = idx >> 3, q = idx & 7;
            const float v[4] = {fmaxf(ga[c][0].x, 0.f), fmaxf(ga[c][0].y, 0.f),
                                fmaxf(ga[c][0].z, 0.f), fmaxf(ga[c][0].w, 0.f)};
            u16x4 hh, ll;
            hh.x = f2bf(v[0]); ll.x = f2bf(v[0] - bf2f(hh.x));
            hh.y = f2bf(v[1]); ll.y = f2bf(v[1] - bf2f(hh.y));
            hh.z = f2bf(v[2]); ll.z = f2bf(v[2] - bf2f(hh.z));
            hh.w = f2bf(v[3]); ll.w = f2bf(v[3] - bf2f(hh.w));
            const int kg = q >> 1, half = (q & 1) * 4;
            *(u16x4*)&L[buf][0][kg * 528 + row * 8 + half] = hh;
            *(u16x4*)&L[buf][1][kg * 528 + row * 8 + half] = ll;
        }
        {
            const int row = t >> 2, kg = t & 3;
            *(u16x8*)&L[buf][2][kg * 528 + row * 8] = gb[0];
            *(u16x8*)&L[buf][3][kg * 528 + row * 8] = gb[1];
        }
    };

    const int wv = t >> 6;
    const int r0 = (wv >> 1) * 32, c0 = (wv & 1) * 32;
    const int lane = t & 63, lr = lane & 15, kg = lane >> 4;

    f32x4 accH[2][2] = {};
    f32x4 accL[2][2] = {};
    stage_load(0);
    stage_write(0);
    __syncthreads();
    for (int kt = 0; kt < nk; ++kt) {
        const int buf = kt & 1;
        if (kt + 1 < nk) stage_load(kt + 1);
        const short* lb = (const short*)&L[buf][0][0];
        bf16x8 fah[2], fal[2], fbh[2], fbl[2];
        #pragma unroll
        for (int rt = 0; rt < 2; ++rt) {
            const int o = kg * 528 + (r0 + rt * 16 + lr) * 8;
            fah[rt] = *(const bf16x8*)(lb + o);
            fal[rt] = *(const bf16x8*)(lb + 2112 + o);
        }
        #pragma unroll
        for (int ct = 0; ct < 2; ++ct) {
            const int o = kg * 528 + (c0 + ct * 16 + lr) * 8;
            fbh[ct] = *(const bf16x8*)(lb + 4224 + o);
            fbl[ct] = *(const bf16x8*)(lb + 6336 + o);
        }
        #pragma unroll
        for (int rt = 0; rt < 2; ++rt)
            #pragma unroll
            for (int ct = 0; ct < 2; ++ct) {
                accH[rt][ct] = __builtin_amdgcn_mfma_f32_16x16x32_bf16(
                                   fah[rt], fbh[ct], accH[rt][ct], 0, 0, 0);
                accL[rt][ct] = __builtin_amdgcn_mfma_f32_16x16x32_bf16(
                                   fah[rt], fbl[ct], accL[rt][ct], 0, 0, 0);
                accL[rt][ct] = __builtin_amdgcn_mfma_f32_16x16x32_bf16(
                                   fal[rt], fbh[ct], accL[rt][ct], 0, 0, 0);
            }
        if (kt + 1 < nk) stage_write(buf ^ 1);
        __syncthreads();
    }

    float* Cb = P3 + (long)sk * 196608;
    #pragma unroll
    for (int rt = 0; rt < 2; ++rt)
        #pragma unroll
        for (int ct = 0; ct < 2; ++ct)
            #pragma unroll
            for (int j = 0; j < 4; ++j)
                Cb[(long)(m0 + r0 + rt * 16 + kg * 4 + j) * 192 +
                   (n0 + c0 + ct * 16 + lr)] = accH[rt][ct][j] + accL[rt][ct][j];
}

// ---------------- ode: GEMM3 8-way reduce + basis/rhs/trapezoid, 4 b/block ----
__global__ __launch_bounds__(256)
void ode_kernel(const float* __restrict__ P3, const float* __restrict__ nb3,
                const float* __restrict__ xi, float* __restrict__ varp,
                float* __restrict__ out0, float* __restrict__ steps,
                float* __restrict__ eps)
{
    const int t  = threadIdx.x;
    const int bl = t >> 6;
    const int b  = blockIdx.x * 4 + bl;
    const int lt = t & 63;
    __shared__ float s_var[4][152];
    __shared__ float s_xi[30];
    __shared__ float s_rhs[4][50][3];
    if (t < 30) s_xi[t] = xi[t];
    for (int i = lt; i < 150; i += 64) {
        float v = nb3[i];
        #pragma unroll
        for (int s = 0; s < 8; ++s) v += P3[s * 196608 + b * 192 + i];
        s_var[bl][i] = v;
        varp[b * 150 + i] = v;
    }
    __syncthreads();
    if (lt < 50) {
        const float v0 = s_var[bl][lt * 3 + 0];
        const float v1 = s_var[bl][lt * 3 + 1];
        const float v2 = s_var[bl][lt * 3 + 2];
        const float bas[10] = {1.f, v0, v1, v2,
                               v0 * v0, v0 * v1, v0 * v2,
                               v1 * v1, v1 * v2, v2 * v2};
        #pragma unroll
        for (int d = 0; d < 3; ++d) {
            float r = 0.f;
            #pragma unroll
            for (int k = 0; k < 10; ++k) r = fmaf(bas[k], s_xi[k * 3 + d], r);
            s_rhs[bl][lt][d] = r;
        }
    }
    __syncthreads();
    if (lt < 3) {
        float x = s_var[bl][lt];              // iv = var[b,0,lt]
        out0[b * 150 + lt] = x;
        for (int n = 1; n < 50; ++n) {
            x = fmaf(0.005f, s_rhs[bl][n - 1][lt] + s_rhs[bl][n][lt], x);
            out0[b * 150 + n * 3 + lt] = x;
        }
        eps[b * 3 + lt] = 0.f;
    }
    for (int i = lt; i < 147; i += 64) steps[b * 147 + i] = 0.01f;
}

extern "C" void kernel_launch(void* const* d_in, const int* in_sizes, int n_in,
                              void* d_out, int out_size, void* d_ws, size_t ws_size,
                              hipStream_t stream)
{
    const float* net_iv   = (const float*)d_in[0];
    const float* param_in = (const float*)d_in[1];
    const float* pW1 = (const float*)d_in[2];
    const float* pb1 = (const float*)d_in[3];
    const float* pW2 = (const float*)d_in[4];
    const float* pb2 = (const float*)d_in[5];
    const float* pW3 = (const float*)d_in[6];
    const float* pb3 = (const float*)d_in[7];
    const float* nW1 = (const float*)d_in[8];
    const float* nb1 = (const float*)d_in[9];
    const float* nW2 = (const float*)d_in[10];
    const float* nb2 = (const float*)d_in[11];
    const float* nW3 = (const float*)d_in[12];
    const float* nb3 = (const float*)d_in[13];
    const float* mask= (const float*)d_in[14];

    float* out = (float*)d_out;
    float* out0p  = out + OUT0_OFF;
    float* stepsp = out + STEPS_OFF;
    float* epsp   = out + EPS_OFF;
    float* varp   = out + VAR_OFF;
    float* xip    = out + XI_OFF;

    // ws layout: bf16 buffers then f32. ~24 MB of 256 MiB.
    unsigned short* H1h  = (unsigned short*)d_ws;     // 1024x1024 each
    unsigned short* H1l  = H1h + 1048576;
    unsigned short* W2Th = H1l + 1048576;             // [n][k]
    unsigned short* W2Tl = W2Th + 1048576;
    unsigned short* B3Th = W2Tl + 1048576;            // [192][1024]
    unsigned short* B3Tl = B3Th + 196608;
    float* P2   = (float*)(B3Tl + 196608);            // 2 x 1048576 f32
    float* P3   = P2 + 2097152;                       // 8 x 196608 f32
    float* part = P3 + 1572864;                       // 16 x 1024
    float* hvec = part + 16384;                       // 1024
    float* h1p  = hvec + 1024;                        // 1024

    // k0: transposes + mv1 (bx==19)
    hipLaunchKernelGGL(transp_both, dim3(20, 16), dim3(256), 0, stream,
                       nW2, W2Th, W2Tl, nW3, B3Th, B3Tl,
                       param_in, pW1, pb1, h1p);

    // k1: GEMM1 -> H1 hi/lo (+ mv2_part piggyback on bx==16)
    hipLaunchKernelGGL(gemm1_k150, dim3(17, 32), dim3(128), 0, stream,
                       net_iv, nW1, nb1, H1h, H1l, h1p, pW2, part);

    // k2: GEMM2 MFMA 64x64, SK=2, K-step 64 full-line staging, XCD swizzle
    //     (+ mv2-reduce on z==2)
    hipLaunchKernelGGL(gemm2_mfma, dim3(16, 16, 3), dim3(256), 0, stream,
                       H1h, H1l, W2Th, W2Tl, P2, part, pb2, hvec);

    // k3: GEMM3 MFMA 64x64, SK=8, XCD co-located; A-stage fuses P2-reduce
    //     + bias + relu + hi/lo split (+ mv3 on bxi==3, reads hvec)
    hipLaunchKernelGGL(gemm3_mfma, dim3(64, 8), dim3(256), 0, stream,
                       P2, nb2, B3Th, B3Tl, P3, hvec, pW3, pb3, mask, xip);

    // k4: ode (reduce 8 partials + basis/rhs/trapezoid + fills)
    hipLaunchKernelGGL(ode_kernel, dim3(256), dim3(256), 0, stream,
                       P3, nb3, xip, varp, out0p, stepsp, epsp);
}

// Round 24
// 56.000 us; speedup vs baseline: 1.1428x; 1.1428x over previous
//
#include <hip/hip_runtime.h>

// Output layout (flat f32, reference return order):
//   out0 : (1024,50,3)  @ 0       (153600)
//   steps: (1024,3,49)  @ 153600  (150528)  all 0.01
//   eps  : (1024,3)     @ 304128  (3072)    analytic 0
//   var  : (1024,50,3)  @ 307200  (153600)
//   xi   : (1,10,3)     @ 460800  (30)
#define OUT0_OFF  0
#define STEPS_OFF 153600
#define EPS_OFF   304128
#define VAR_OFF   307200
#define XI_OFF    460800

typedef short bf16x8 __attribute__((ext_vector_type(8)));
typedef float f32x4  __attribute__((ext_vector_type(4)));
typedef unsigned short u16x8 __attribute__((ext_vector_type(8)));
typedef unsigned short u16x4 __attribute__((ext_vector_type(4)));

__device__ __forceinline__ unsigned short f2bf(float x) {   // RNE f32->bf16
    union { float f; unsigned u; } c; c.f = x;
    return (unsigned short)((c.u + 0x7FFFu + ((c.u >> 16) & 1u)) >> 16);
}
__device__ __forceinline__ float bf2f(unsigned short h) {
    union { float f; unsigned u; } c; c.u = ((unsigned)h) << 16;
    return c.f;
}

__device__ __forceinline__ void fma16v(const float4& av, const float4& bv,
                                       float acc[4][4]) {
    const float a_[4] = {av.x, av.y, av.z, av.w};
    const float b_[4] = {bv.x, bv.y, bv.z, bv.w};
    #pragma unroll
    for (int i = 0; i < 4; ++i)
        #pragma unroll
        for (int j = 0; j < 4; ++j)
            acc[i][j] = fmaf(a_[i], b_[j], acc[i][j]);
}

// ------- transpose+split (bx<16: nW2; 16<=bx<19: nW3) + mv1 (bx==19) ----------
__global__ __launch_bounds__(256)
void transp_both(const float* __restrict__ w2,
                 unsigned short* __restrict__ t2h, unsigned short* __restrict__ t2l,
                 const float* __restrict__ w3,
                 unsigned short* __restrict__ t3h, unsigned short* __restrict__ t3l,
                 const float* __restrict__ px, const float* __restrict__ pW1,
                 const float* __restrict__ pb1, float* __restrict__ h1p)
{
    __shared__ float Ts[64][65];
    const int t = threadIdx.x;

    if (blockIdx.x == 19) {                       // mv1: 16 blocks x 64 j
        float* red = &Ts[0][0];                   // [4][64]
        const int jl = t & 63, kg = t >> 6;       // 4 kgroups x 16 k
        const int j = blockIdx.y * 64 + jl;
        float acc = 0.f;
        for (int k = kg * 16; k < kg * 16 + 16; ++k)
            acc = fmaf(px[k], pW1[k * 1024 + j], acc);
        red[kg * 64 + jl] = acc;
        __syncthreads();
        if (kg == 0) {
            float s = red[jl] + red[64 + jl] + red[128 + jl] + red[192 + jl];
            h1p[j] = fmaxf(s + pb1[j], 0.f);
        }
        return;
    }

    const bool w3path = blockIdx.x >= 16;
    const int n0 = (w3path ? (blockIdx.x - 16) : blockIdx.x) * 64;
    const int k0 = blockIdx.y * 64;
    const int g = t >> 6;
    const int l = t & 63;
    #pragma unroll
    for (int i = 0; i < 16; ++i) {
        const int kl = g * 16 + i;
        if (w3path) {
            const int n = n0 + l;
            Ts[kl][l] = (n < 150) ? w3[(k0 + kl) * 150 + n] : 0.f;
        } else {
            Ts[kl][l] = w2[(k0 + kl) * 1024 + n0 + l];
        }
    }
    __syncthreads();
    unsigned short* th = w3path ? t3h : t2h;
    unsigned short* tl = w3path ? t3l : t2l;
    #pragma unroll
    for (int i = 0; i < 16; ++i) {
        const int nl = g * 16 + i;
        const float x = Ts[l][nl];
        const unsigned short h = f2bf(x);
        th[(long)(n0 + nl) * 1024 + k0 + l] = h;
        tl[(long)(n0 + nl) * 1024 + k0 + l] = f2bf(x - bf2f(h));
    }
}

// ---------------- GEMM1: H1 = relu(net_iv @ nW1 + nb1) -> bf16 hi/lo ----------
__global__ __launch_bounds__(128)
void gemm1_k150(const float* __restrict__ A, const float* __restrict__ B,
                const float* __restrict__ bias,
                unsigned short* __restrict__ H1h, unsigned short* __restrict__ H1l)
{
    __shared__ __align__(16) float As[150][36];   // transposed A, 21.6 KB
    __shared__ __align__(16) float Bs[150][64];   // 38.4 KB
    const int t = threadIdx.x;

    const int col0 = blockIdx.x * 64;
    const int row0 = blockIdx.y * 32;

    for (int i = t; i < 4800; i += 128) {
        const int r = i / 150;
        const int k = i - r * 150;
        As[k][r] = A[row0 * 150 + i];
    }
    {
        const int c4 = (t & 15) * 4;
        for (int k = t >> 4; k < 150; k += 8)
            *(float4*)&Bs[k][c4] = *(const float4*)(B + k * 1024 + col0 + c4);
    }
    __syncthreads();

    const int tx4 = (t & 15) * 4;
    const int ty4 = (t >> 4) * 4;
    float acc[4][4] = {};
    float4 aA = *(const float4*)&As[0][ty4], bA = *(const float4*)&Bs[0][tx4];
    float4 aB = *(const float4*)&As[1][ty4], bB = *(const float4*)&Bs[1][tx4];
    #pragma unroll 5
    for (int k = 0; k < 150; k += 2) {
        float4 aN0 = {}, bN0 = {}, aN1 = {}, bN1 = {};
        if (k + 2 < 150) {
            aN0 = *(const float4*)&As[k + 2][ty4];
            bN0 = *(const float4*)&Bs[k + 2][tx4];
        }
        if (k + 3 < 150) {
            aN1 = *(const float4*)&As[k + 3][ty4];
            bN1 = *(const float4*)&Bs[k + 3][tx4];
        }
        fma16v(aA, bA, acc);
        fma16v(aB, bB, acc);
        aA = aN0; bA = bN0; aB = aN1; bB = bN1;
    }
    #pragma unroll
    for (int i = 0; i < 4; ++i) {
        const int r = row0 + ty4 + i;
        #pragma unroll
        for (int j = 0; j < 4; ++j) {
            const int c = col0 + tx4 + j;
            const float v = fmaxf(acc[i][j] + bias[c], 0.f);
            const unsigned short h = f2bf(v);
            H1h[r * 1024 + c] = h;
            H1l[r * 1024 + c] = f2bf(v - bf2f(h));
        }
    }
}

// ---------------- mv2_part: part[ks][j] = sum_{k in slice} h1p[k]*pW2[k][j] ---
__global__ __launch_bounds__(256)
void mv2_part(const float* __restrict__ h1p, const float* __restrict__ pW2,
              float* __restrict__ part)
{
    const int b = blockIdx.x;                     // 0..63
    const int j = (b & 3) * 256 + threadIdx.x;
    const int k0 = (b >> 2) * 64;
    float a0 = 0.f, a1 = 0.f, a2 = 0.f, a3 = 0.f;
    #pragma unroll
    for (int k = k0; k < k0 + 64; k += 4) {
        a0 = fmaf(h1p[k + 0], pW2[(k + 0) * 1024 + j], a0);
        a1 = fmaf(h1p[k + 1], pW2[(k + 1) * 1024 + j], a1);
        a2 = fmaf(h1p[k + 2], pW2[(k + 2) * 1024 + j], a2);
        a3 = fmaf(h1p[k + 3], pW2[(k + 3) * 1024 + j], a3);
    }
    part[(b >> 2) * 1024 + j] = (a0 + a1) + (a2 + a3);
}

// ---------------- gemm2_mfma: 64x64 tile, split-K=2, K-step 64 ----------------
// Full-cache-line staging: 8 lanes x 16 B per row = 128 B lines, each line
// fetched once. nk=8. Per kt, the two 32-k halves run in the old order ->
// bit-identical accumulation. XCD-tile swizzle kept.
// z==2 layer: 4 blocks reduce mv2 partials -> hvec.
__global__ __launch_bounds__(256, 1)
void gemm2_mfma(const unsigned short* __restrict__ Ah, const unsigned short* __restrict__ Al,
                const unsigned short* __restrict__ Bh, const unsigned short* __restrict__ Bl,
                float* __restrict__ P2,
                const float* __restrict__ part, const float* __restrict__ pb2,
                float* __restrict__ hvec)
{
    // [buf][mat 4][kg8 * 528 + row * 8] shorts = 67.6 KB -> 2 blocks/CU
    __shared__ __align__(16) unsigned short L[2][4][4224];
    const int t = threadIdx.x;

    if (blockIdx.z == 2) {                         // mv2 reduce: 4 blocks
        const int idx = blockIdx.y * 16 + blockIdx.x;
        if (idx >= 4) return;
        const int j = idx * 256 + t;
        float s = 0.f;
        #pragma unroll
        for (int sl2 = 0; sl2 < 16; ++sl2) s += part[sl2 * 1024 + j];
        hvec[j] = fmaxf(s + pb2[j], 0.f);
        return;
    }

    // XCD-tile swizzle: xcd = x%8; per-XCD working set 3 MB <= 4 MB L2.
    const int x = blockIdx.x, y = blockIdx.y;
    const int xcd = x & 7;
    const int v   = ((x >> 3) << 4) + y;           // 0..31
    const int by  = (xcd >> 1) * 4 + (v & 3);      // 0..15
    const int bx  = (xcd & 1) * 8 + (v >> 2);      // 0..15
    const int m0 = by * 64;
    const int n0 = bx * 64;
    const int K = 1024, nk = 8;                    // kchunk 512, K-step 64
    const long kbase = (long)blockIdx.z * 512;

    const int sm = t >> 6;                         // wave stages one matrix
    const int sl = t & 63;
    const unsigned short* src = (sm == 0) ? Ah : (sm == 1) ? Al
                              : (sm == 2) ? Bh : Bl;
    const int srow0 = (sm < 2) ? m0 : n0;

    u16x8 gv[8];
    auto stage_load = [&](int kt) {                // T14: issue early
        const long kb = kbase + (long)kt * 64;
        #pragma unroll
        for (int c2 = 0; c2 < 8; ++c2) {
            const int flat = c2 * 64 + sl;
            const int row = flat >> 3, kg = flat & 7;   // 8 lanes/row = 128 B
            gv[c2] = *(const u16x8*)(src + (long)(srow0 + row) * K + kb + kg * 8);
        }
    };
    auto stage_write = [&](int buf) {              // T14: write late
        #pragma unroll
        for (int c2 = 0; c2 < 8; ++c2) {
            const int flat = c2 * 64 + sl;
            const int row = flat >> 3, kg = flat & 7;
            *(u16x8*)&L[buf][sm][kg * 528 + row * 8] = gv[c2];
        }
    };

    const int wv = t >> 6;
    const int r0 = (wv >> 1) * 32, c0 = (wv & 1) * 32;
    const int lane = t & 63, lr = lane & 15, kq = lane >> 4;

    f32x4 accH[2][2] = {};
    f32x4 accL[2][2] = {};
    stage_load(0);
    stage_write(0);
    __syncthreads();
    for (int kt = 0; kt < nk; ++kt) {
        const int buf = kt & 1;
        if (kt + 1 < nk) stage_load(kt + 1);
        const short* lb = (const short*)&L[buf][0][0];
        #pragma unroll
        for (int h = 0; h < 2; ++h) {              // two 32-k halves, old order
            const int kgf = kq + h * 4;
            bf16x8 fah[2], fal[2], fbh[2], fbl[2];
            #pragma unroll
            for (int rt = 0; rt < 2; ++rt) {
                const int o = kgf * 528 + (r0 + rt * 16 + lr) * 8;
                fah[rt] = *(const bf16x8*)(lb + o);
                fal[rt] = *(const bf16x8*)(lb + 4224 + o);
            }
            #pragma unroll
            for (int ct = 0; ct < 2; ++ct) {
                const int o = kgf * 528 + (c0 + ct * 16 + lr) * 8;
                fbh[ct] = *(const bf16x8*)(lb + 8448 + o);
                fbl[ct] = *(const bf16x8*)(lb + 12672 + o);
            }
            #pragma unroll
            for (int rt = 0; rt < 2; ++rt)
                #pragma unroll
                for (int ct = 0; ct < 2; ++ct) {
                    accH[rt][ct] = __builtin_amdgcn_mfma_f32_16x16x32_bf16(
                                       fah[rt], fbh[ct], accH[rt][ct], 0, 0, 0);
                    accL[rt][ct] = __builtin_amdgcn_mfma_f32_16x16x32_bf16(
                                       fah[rt], fbl[ct], accL[rt][ct], 0, 0, 0);
                    accL[rt][ct] = __builtin_amdgcn_mfma_f32_16x16x32_bf16(
                                       fal[rt], fbh[ct], accL[rt][ct], 0, 0, 0);
                }
        }
        if (kt + 1 < nk) stage_write(buf ^ 1);
        __syncthreads();
    }

    // C/D layout: row = (lane>>4)*4 + j, col = lane&15  [m89-verified]
    float* Cb = P2 + (long)blockIdx.z * 1048576;
    #pragma unroll
    for (int rt = 0; rt < 2; ++rt)
        #pragma unroll
        for (int ct = 0; ct < 2; ++ct)
            #pragma unroll
            for (int j = 0; j < 4; ++j)
                Cb[(long)(m0 + r0 + rt * 16 + kq * 4 + j) * 1024 +
                   (n0 + c0 + ct * 16 + lr)] = accH[rt][ct][j] + accL[rt][ct][j];
}

// ---------------- gemm3_mfma: A-stage fuses P2-reduce+bias+relu+split ---------
// Grid (64,8), XCD co-located A-panels; bxi==3 -> mv3 (reads hvec).
__global__ __launch_bounds__(256, 1)
void gemm3_mfma(const float* __restrict__ P2, const float* __restrict__ nb2,
                const unsigned short* __restrict__ Bh, const unsigned short* __restrict__ Bl,
                float* __restrict__ P3,
                const float* __restrict__ hvec,
                const float* __restrict__ pW3, const float* __restrict__ pb3,
                const float* __restrict__ mask, float* __restrict__ xi)
{
    __shared__ __align__(16) unsigned short L[2][4][2112];
    const int t = threadIdx.x;

    const int g   = blockIdx.x;                    // 0..63
    const int sk  = blockIdx.y;                    // 0..7
    const int bxi = (g >> 3) & 3;                  // 0..3
    const int by  = (g & 7) + ((g >> 5) << 3);     // 0..15

    if (bxi == 3) {                                // mv3: 15 blocks x 2 j
        const int idx = by * 8 + sk;
        if (idx >= 15) return;
        const int j = idx * 2 + (t >> 7);
        const int lane = t & 127;
        float acc = 0.f;
        for (int k = lane; k < 1024; k += 128)
            acc = fmaf(hvec[k], pW3[k * 30 + j], acc);
        #pragma unroll
        for (int off = 32; off > 0; off >>= 1) acc += __shfl_down(acc, off, 64);
        float* red = (float*)&L[0][0][0];
        if ((t & 63) == 0) red[t >> 6] = acc;
        __syncthreads();
        if ((t & 127) == 0)
            xi[j] = (red[t >> 6] + red[(t >> 6) + 1] + pb3[j]) * mask[j];
        return;
    }

    const int m0 = by * 64;
    const int n0 = bxi * 64;
    const int nk = 4;                              // kchunk 128
    const long kbase = (long)sk * 128;

    float4 ga[2][2];                               // [c][partial-sum parts]
    u16x8 gb[2];
    auto stage_load = [&](int kt) {
        const long kb = kbase + (long)kt * 32;
        #pragma unroll
        for (int c = 0; c < 2; ++c) {
            const int idx = c * 256 + t;           // 0..511
            const int row = idx >> 3, q = idx & 7; // 64 rows x 8 f32-quads
            const long o = (long)(m0 + row) * 1024 + kb + q * 4;
            float4 p = *(const float4*)(P2 + o);
            float4 s = *(const float4*)(P2 + 1048576 + o);
            float4 bv = *(const float4*)(nb2 + kb + q * 4);
            ga[c][0].x = p.x + s.x + bv.x; ga[c][0].y = p.y + s.y + bv.y;
            ga[c][0].z = p.z + s.z + bv.z; ga[c][0].w = p.w + s.w + bv.w;
            ga[c][1] = ga[c][0];                   // placeholder (unused slot)
        }
        {
            const int row = t >> 2, kg = t & 3;    // 64 rows x 4 kgroups
            const long o = (long)(n0 + row) * 1024 + kb + kg * 8;
            gb[0] = *(const u16x8*)(Bh + o);
            gb[1] = *(const u16x8*)(Bl + o);
        }
    };
    auto stage_write = [&](int buf) {
        #pragma unroll
        for (int c = 0; c < 2; ++c) {
            const int idx = c * 256 + t;
            const int row = idx >> 3, q = idx & 7;
            const float v[4] = {fmaxf(ga[c][0].x, 0.f), fmaxf(ga[c][0].y, 0.f),
                                fmaxf(ga[c][0].z, 0.f), fmaxf(ga[c][0].w, 0.f)};
            u16x4 hh, ll;
            hh.x = f2bf(v[0]); ll.x = f2bf(v[0] - bf2f(hh.x));
            hh.y = f2bf(v[1]); ll.y = f2bf(v[1] - bf2f(hh.y));
            hh.z = f2bf(v[2]); ll.z = f2bf(v[2] - bf2f(hh.z));
            hh.w = f2bf(v[3]); ll.w = f2bf(v[3] - bf2f(hh.w));
            const int kg = q >> 1, half = (q & 1) * 4;
            *(u16x4*)&L[buf][0][kg * 528 + row * 8 + half] = hh;
            *(u16x4*)&L[buf][1][kg * 528 + row * 8 + half] = ll;
        }
        {
            const int row = t >> 2, kg = t & 3;
            *(u16x8*)&L[buf][2][kg * 528 + row * 8] = gb[0];
            *(u16x8*)&L[buf][3][kg * 528 + row * 8] = gb[1];
        }
    };

    const int wv = t >> 6;
    const int r0 = (wv >> 1) * 32, c0 = (wv & 1) * 32;
    const int lane = t & 63, lr = lane & 15, kg = lane >> 4;

    f32x4 accH[2][2] = {};
    f32x4 accL[2][2] = {};
    stage_load(0);
    stage_write(0);
    __syncthreads();
    for (int kt = 0; kt < nk; ++kt) {
        const int buf = kt & 1;
        if (kt + 1 < nk) stage_load(kt + 1);
        const short* lb = (const short*)&L[buf][0][0];
        bf16x8 fah[2], fal[2], fbh[2], fbl[2];
        #pragma unroll
        for (int rt = 0; rt < 2; ++rt) {
            const int o = kg * 528 + (r0 + rt * 16 + lr) * 8;
            fah[rt] = *(const bf16x8*)(lb + o);
            fal[rt] = *(const bf16x8*)(lb + 2112 + o);
        }
        #pragma unroll
        for (int ct = 0; ct < 2; ++ct) {
            const int o = kg * 528 + (c0 + ct * 16 + lr) * 8;
            fbh[ct] = *(const bf16x8*)(lb + 4224 + o);
            fbl[ct] = *(const bf16x8*)(lb + 6336 + o);
        }
        #pragma unroll
        for (int rt = 0; rt < 2; ++rt)
            #pragma unroll
            for (int ct = 0; ct < 2; ++ct) {
                accH[rt][ct] = __builtin_amdgcn_mfma_f32_16x16x32_bf16(
                                   fah[rt], fbh[ct], accH[rt][ct], 0, 0, 0);
                accL[rt][ct] = __builtin_amdgcn_mfma_f32_16x16x32_bf16(
                                   fah[rt], fbl[ct], accL[rt][ct], 0, 0, 0);
                accL[rt][ct] = __builtin_amdgcn_mfma_f32_16x16x32_bf16(
                                   fal[rt], fbh[ct], accL[rt][ct], 0, 0, 0);
            }
        if (kt + 1 < nk) stage_write(buf ^ 1);
        __syncthreads();
    }

    float* Cb = P3 + (long)sk * 196608;
    #pragma unroll
    for (int rt = 0; rt < 2; ++rt)
        #pragma unroll
        for (int ct = 0; ct < 2; ++ct)
            #pragma unroll
            for (int j = 0; j < 4; ++j)
                Cb[(long)(m0 + r0 + rt * 16 + kg * 4 + j) * 192 +
                   (n0 + c0 + ct * 16 + lr)] = accH[rt][ct][j] + accL[rt][ct][j];
}

// ---------------- ode: GEMM3 8-way reduce + basis/rhs/trapezoid, 4 b/block ----
__global__ __launch_bounds__(256)
void ode_kernel(const float* __restrict__ P3, const float* __restrict__ nb3,
                const float* __restrict__ xi, float* __restrict__ varp,
                float* __restrict__ out0, float* __restrict__ steps,
                float* __restrict__ eps)
{
    const int t  = threadIdx.x;
    const int bl = t >> 6;
    const int b  = blockIdx.x * 4 + bl;
    const int lt = t & 63;
    __shared__ float s_var[4][152];
    __shared__ float s_xi[30];
    __shared__ float s_rhs[4][50][3];
    if (t < 30) s_xi[t] = xi[t];
    for (int i = lt; i < 150; i += 64) {
        float v = nb3[i];
        #pragma unroll
        for (int s = 0; s < 8; ++s) v += P3[s * 196608 + b * 192 + i];
        s_var[bl][i] = v;
        varp[b * 150 + i] = v;
    }
    __syncthreads();
    if (lt < 50) {
        const float v0 = s_var[bl][lt * 3 + 0];
        const float v1 = s_var[bl][lt * 3 + 1];
        const float v2 = s_var[bl][lt * 3 + 2];
        const float bas[10] = {1.f, v0, v1, v2,
                               v0 * v0, v0 * v1, v0 * v2,
                               v1 * v1, v1 * v2, v2 * v2};
        #pragma unroll
        for (int d = 0; d < 3; ++d) {
            float r = 0.f;
            #pragma unroll
            for (int k = 0; k < 10; ++k) r = fmaf(bas[k], s_xi[k * 3 + d], r);
            s_rhs[bl][lt][d] = r;
        }
    }
    __syncthreads();
    if (lt < 3) {
        float x = s_var[bl][lt];              // iv = var[b,0,lt]
        out0[b * 150 + lt] = x;
        for (int n = 1; n < 50; ++n) {
            x = fmaf(0.005f, s_rhs[bl][n - 1][lt] + s_rhs[bl][n][lt], x);
            out0[b * 150 + n * 3 + lt] = x;
        }
        eps[b * 3 + lt] = 0.f;
    }
    for (int i = lt; i < 147; i += 64) steps[b * 147 + i] = 0.01f;
}

extern "C" void kernel_launch(void* const* d_in, const int* in_sizes, int n_in,
                              void* d_out, int out_size, void* d_ws, size_t ws_size,
                              hipStream_t stream)
{
    const float* net_iv   = (const float*)d_in[0];
    const float* param_in = (const float*)d_in[1];
    const float* pW1 = (const float*)d_in[2];
    const float* pb1 = (const float*)d_in[3];
    const float* pW2 = (const float*)d_in[4];
    const float* pb2 = (const float*)d_in[5];
    const float* pW3 = (const float*)d_in[6];
    const float* pb3 = (const float*)d_in[7];
    const float* nW1 = (const float*)d_in[8];
    const float* nb1 = (const float*)d_in[9];
    const float* nW2 = (const float*)d_in[10];
    const float* nb2 = (const float*)d_in[11];
    const float* nW3 = (const float*)d_in[12];
    const float* nb3 = (const float*)d_in[13];
    const float* mask= (const float*)d_in[14];

    float* out = (float*)d_out;
    float* out0p  = out + OUT0_OFF;
    float* stepsp = out + STEPS_OFF;
    float* epsp   = out + EPS_OFF;
    float* varp   = out + VAR_OFF;
    float* xip    = out + XI_OFF;

    // ws layout: bf16 buffers then f32. ~24 MB of 256 MiB.
    unsigned short* H1h  = (unsigned short*)d_ws;     // 1024x1024 each
    unsigned short* H1l  = H1h + 1048576;
    unsigned short* W2Th = H1l + 1048576;             // [n][k]
    unsigned short* W2Tl = W2Th + 1048576;
    unsigned short* B3Th = W2Tl + 1048576;            // [192][1024]
    unsigned short* B3Tl = B3Th + 196608;
    float* P2   = (float*)(B3Tl + 196608);            // 2 x 1048576 f32
    float* P3   = P2 + 2097152;                       // 8 x 196608 f32
    float* part = P3 + 1572864;                       // 16 x 1024
    float* hvec = part + 16384;                       // 1024
    float* h1p  = hvec + 1024;                        // 1024

    // k0: transposes + mv1 (bx==19)
    hipLaunchKernelGGL(transp_both, dim3(20, 16), dim3(256), 0, stream,
                       nW2, W2Th, W2Tl, nW3, B3Th, B3Tl,
                       param_in, pW1, pb1, h1p);

    // k1: GEMM1 -> H1 hi/lo
    hipLaunchKernelGGL(gemm1_k150, dim3(16, 32), dim3(128), 0, stream,
                       net_iv, nW1, nb1, H1h, H1l);

    // k2: mv2 partials (64 blocks, short coalesced chains)
    hipLaunchKernelGGL(mv2_part, dim3(64), dim3(256), 0, stream,
                       h1p, pW2, part);

    // k3: GEMM2 MFMA 64x64, SK=2, K-step 64 full-line staging, XCD swizzle
    //     (+ mv2-reduce on z==2)
    hipLaunchKernelGGL(gemm2_mfma, dim3(16, 16, 3), dim3(256), 0, stream,
                       H1h, H1l, W2Th, W2Tl, P2, part, pb2, hvec);

    // k4: GEMM3 MFMA 64x64, SK=8, XCD co-located; A-stage fuses P2-reduce
    //     + bias + relu + hi/lo split (+ mv3 on bxi==3, reads hvec)
    hipLaunchKernelGGL(gemm3_mfma, dim3(64, 8), dim3(256), 0, stream,
                       P2, nb2, B3Th, B3Tl, P3, hvec, pW3, pb3, mask, xip);

    // k5: ode (reduce 8 partials + basis/rhs/trapezoid + fills)
    hipLaunchKernelGGL(ode_kernel, dim3(256), dim3(256), 0, stream,
                       P3, nb3, xip, varp, out0p, stepsp, epsp);
}